// Round 2
// baseline (248.811 us; speedup 1.0000x reference)
//
#include <hip/hip_runtime.h>
#include <hip/hip_bf16.h>
#include <math.h>

// Problem constants
#define TT   16384   // tokens = 8*2048
#define DIN  1024
#define DOUT 1024
#define NEXP 8
#define RANK 32
#define KCAT 256     // NEXP*RANK

using bf16 = __hip_bfloat16;
typedef __attribute__((ext_vector_type(8))) short short8;
typedef __attribute__((ext_vector_type(4))) short short4v;
typedef __attribute__((ext_vector_type(4))) float f32x4;

static __device__ __forceinline__ float b2f(bf16 v) { return __bfloat162float(v); }
static __device__ __forceinline__ bf16  f2b(float v) { return __float2bfloat16(v); }

// async global->LDS, 16B per lane; lds dest is wave-uniform base (+lane*16 implied)
static __device__ __forceinline__ void load_lds16(const bf16* g, bf16* l) {
  __builtin_amdgcn_global_load_lds(
      (const __attribute__((address_space(1))) void*)g,
      (__attribute__((address_space(3))) void*)l, 16, 0, 0);
}

// ---------------- cvt: f32 -> bf16, vectorized ----------------
__global__ __launch_bounds__(256) void cvt_kernel(const float* __restrict__ in,
                                                  bf16* __restrict__ out, int n4) {
  for (int i = blockIdx.x * blockDim.x + threadIdx.x; i < n4;
       i += gridDim.x * blockDim.x) {
    float4 v = ((const float4*)in)[i];
    union { short4v s; bf16 b[4]; } u;
    u.b[0] = f2b(v.x); u.b[1] = f2b(v.y); u.b[2] = f2b(v.z); u.b[3] = f2b(v.w);
    ((short4v*)out)[i] = u.s;
  }
}

// ---------------- prep: A_cat [256][1024] bf16, B_catT [1024][256] bf16 ----------------
__global__ __launch_bounds__(256) void prep_kernel(const float* __restrict__ A,
                                                   const float* __restrict__ Sa,
                                                   const float* __restrict__ B,
                                                   const float* __restrict__ Sb,
                                                   bf16* __restrict__ Acat,
                                                   bf16* __restrict__ BcatT) {
  const int n = NEXP * RANK * DIN; // 262144
  for (int idx = blockIdx.x * blockDim.x + threadIdx.x; idx < n;
       idx += gridDim.x * blockDim.x) {
    // A_cat: same flat layout as A ([E,R,D] -> [256][1024])
    float a = A[idx];
    float s = Sa[idx];
    Acat[idx] = f2b(a * (1.0f / (1.0f + __expf(-s))));
    // B_catT[o][j], j=e*32+r  <-  B[e, o, r]
    int o = idx >> 8;        // 0..1023
    int j = idx & 255;       // 0..255
    int e = j >> 5, r = j & 31;
    int src = e * (DOUT * RANK) + o * RANK + r;
    float bb = B[src];
    float sb = Sb[src];
    BcatT[idx] = f2b(bb * (1.0f / (1.0f + __expf(-sb))));
  }
}

// ---------------- router: gate [TT][8] f32 ----------------
__global__ __launch_bounds__(64) void router_kernel(const bf16* __restrict__ xb,
                                                    const float* __restrict__ rW,
                                                    const float* __restrict__ rb,
                                                    float* __restrict__ gate) {
  const int t = blockIdx.x;
  const int lane = threadIdx.x;
  const bf16* xrow = xb + (size_t)t * DIN;
  const int base = lane * 16;               // each lane covers 16 contiguous dims
  float xv[16];
  {
    short8 x0 = *(const short8*)&xrow[base];
    short8 x1 = *(const short8*)&xrow[base + 8];
    #pragma unroll
    for (int j = 0; j < 8; ++j) {
      union { short s; bf16 b; } u0, u1;
      u0.s = x0[j]; u1.s = x1[j];
      xv[j] = b2f(u0.b); xv[8 + j] = b2f(u1.b);
    }
  }
  float acc[NEXP] = {};
  #pragma unroll
  for (int e = 0; e < NEXP; ++e) {
    const float4* w4 = (const float4*)&rW[e * DIN + base];
    #pragma unroll
    for (int q = 0; q < 4; ++q) {
      float4 w = w4[q];
      acc[e] += xv[q * 4 + 0] * w.x + xv[q * 4 + 1] * w.y +
                xv[q * 4 + 2] * w.z + xv[q * 4 + 3] * w.w;
    }
  }
  #pragma unroll
  for (int e = 0; e < NEXP; ++e) {
    #pragma unroll
    for (int off = 32; off > 0; off >>= 1)
      acc[e] += __shfl_down(acc[e], off);
  }
  if (lane == 0) {
    float lg[NEXP];
    float mx = -1e30f;
    #pragma unroll
    for (int e = 0; e < NEXP; ++e) { lg[e] = acc[e] + rb[e]; mx = fmaxf(mx, lg[e]); }
    float se = 0.f;
    #pragma unroll
    for (int e = 0; e < NEXP; ++e) { lg[e] = __expf(lg[e] - mx); se += lg[e]; }
    float inv = 1.0f / se;
    int i1 = 0;
    #pragma unroll
    for (int e = 1; e < NEXP; ++e) if (lg[e] > lg[i1]) i1 = e;
    int i2 = (i1 == 0) ? 1 : 0;
    #pragma unroll
    for (int e = 0; e < NEXP; ++e) if (e != i1 && lg[e] > lg[i2]) i2 = e;
    #pragma unroll
    for (int e = 0; e < NEXP; ++e)
      gate[(size_t)t * NEXP + e] = (e == i1 || e == i2) ? lg[e] * inv : 0.0f;
  }
}

// ---------------- gemm1: hg[t][j] = gate[t][j/32] * sum_d xb[t,d]*Acat[j,d] ----------------
// BM=128, BN=64, BK=32; 4 waves as 2x2; wave tile 64x32
__global__ __launch_bounds__(256) void gemm1_kernel(const bf16* __restrict__ xb,
                                                    const bf16* __restrict__ Acat,
                                                    const float* __restrict__ gate,
                                                    bf16* __restrict__ hg) {
  __shared__ alignas(16) bf16 As[128][32];
  __shared__ alignas(16) bf16 Bs[64][32];
  const int tid = threadIdx.x, wid = tid >> 6, lane = tid & 63;
  const int wr = wid >> 1, wc = wid & 1;
  const int tileRow = blockIdx.x * 128, tileCol = blockIdx.y * 64;
  f32x4 acc[4][2] = {};

  for (int kt = 0; kt < DIN / 32; ++kt) {
    const int k0 = kt * 32;
    const int srow = (lane >> 2);
    const int scol = (lane & 3) * 8;
    #pragma unroll
    for (int i = 0; i < 2; ++i) {
      int row = i * 64 + wid * 16 + srow;
      load_lds16(xb + (size_t)(tileRow + row) * DIN + k0 + scol, &As[i * 64 + wid * 16][0]);
    }
    {
      int row = wid * 16 + srow;
      load_lds16(Acat + (size_t)(tileCol + row) * DIN + k0 + scol, &Bs[wid * 16][0]);
    }
    __syncthreads();
    short8 a[4], b[2];
    #pragma unroll
    for (int m = 0; m < 4; ++m)
      a[m] = *(const short8*)&As[wr * 64 + m * 16 + (lane & 15)][(lane >> 4) * 8];
    #pragma unroll
    for (int n = 0; n < 2; ++n)
      b[n] = *(const short8*)&Bs[wc * 32 + n * 16 + (lane & 15)][(lane >> 4) * 8];
    #pragma unroll
    for (int m = 0; m < 4; ++m)
      #pragma unroll
      for (int n = 0; n < 2; ++n)
        acc[m][n] = __builtin_amdgcn_mfma_f32_16x16x32_bf16(a[m], b[n], acc[m][n], 0, 0, 0);
    __syncthreads();
  }

  #pragma unroll
  for (int n = 0; n < 2; ++n) {
    int j = tileCol + wc * 32 + n * 16 + (lane & 15);
    int e = j >> 5;
    #pragma unroll
    for (int m = 0; m < 4; ++m) {
      int row0 = tileRow + wr * 64 + m * 16 + (lane >> 4) * 4;
      #pragma unroll
      for (int r = 0; r < 4; ++r) {
        float g = gate[(size_t)(row0 + r) * NEXP + e];
        hg[(size_t)(row0 + r) * KCAT + j] = f2b(acc[m][n][r] * g);
      }
    }
  }
}

// ---------------- gemm2: y = xb@Wb^T + hg@BcatT^T + b  (K = 1024 | 256) ----------------
// BM=128, BN=128, BK=32; 4 waves 2x2; wave tile 64x64
__global__ __launch_bounds__(256) void gemm2_kernel(const bf16* __restrict__ xb,
                                                    const bf16* __restrict__ Wb,
                                                    const float* __restrict__ bias,
                                                    const bf16* __restrict__ hg,
                                                    const bf16* __restrict__ BcatT,
                                                    float* __restrict__ out) {
  __shared__ alignas(16) bf16 As[128][32];
  __shared__ alignas(16) bf16 Bs[128][32];
  const int tid = threadIdx.x, wid = tid >> 6, lane = tid & 63;
  const int wr = wid >> 1, wc = wid & 1;
  const int tileRow = blockIdx.x * 128, tileCol = blockIdx.y * 128;
  f32x4 acc[4][4] = {};

  const int KT = (DIN + KCAT) / 32; // 40
  for (int kt = 0; kt < KT; ++kt) {
    const bf16 *aptr, *bptr;
    int lda, k0;
    if (kt < DIN / 32) { aptr = xb; bptr = Wb;    lda = DIN;  k0 = kt * 32; }
    else               { aptr = hg; bptr = BcatT; lda = KCAT; k0 = (kt - DIN / 32) * 32; }
    const int srow = (lane >> 2);
    const int scol = (lane & 3) * 8;
    #pragma unroll
    for (int i = 0; i < 2; ++i) {
      int row = i * 64 + wid * 16 + srow;
      load_lds16(aptr + (size_t)(tileRow + row) * lda + k0 + scol, &As[i * 64 + wid * 16][0]);
    }
    #pragma unroll
    for (int i = 0; i < 2; ++i) {
      int row = i * 64 + wid * 16 + srow;
      load_lds16(bptr + (size_t)(tileCol + row) * lda + k0 + scol, &Bs[i * 64 + wid * 16][0]);
    }
    __syncthreads();
    short8 a[4], b[4];
    #pragma unroll
    for (int m = 0; m < 4; ++m)
      a[m] = *(const short8*)&As[wr * 64 + m * 16 + (lane & 15)][(lane >> 4) * 8];
    #pragma unroll
    for (int n = 0; n < 4; ++n)
      b[n] = *(const short8*)&Bs[wc * 64 + n * 16 + (lane & 15)][(lane >> 4) * 8];
    #pragma unroll
    for (int m = 0; m < 4; ++m)
      #pragma unroll
      for (int n = 0; n < 4; ++n)
        acc[m][n] = __builtin_amdgcn_mfma_f32_16x16x32_bf16(a[m], b[n], acc[m][n], 0, 0, 0);
    __syncthreads();
  }

  #pragma unroll
  for (int n = 0; n < 4; ++n) {
    int col = tileCol + wc * 64 + n * 16 + (lane & 15);
    float bb = bias[col];
    #pragma unroll
    for (int m = 0; m < 4; ++m) {
      int row0 = tileRow + wr * 64 + m * 16 + (lane >> 4) * 4;
      #pragma unroll
      for (int r = 0; r < 4; ++r)
        out[(size_t)(row0 + r) * DOUT + col] = acc[m][n][r] + bb;
    }
  }
}

extern "C" void kernel_launch(void* const* d_in, const int* in_sizes, int n_in,
                              void* d_out, int out_size, void* d_ws, size_t ws_size,
                              hipStream_t stream) {
  const float* x  = (const float*)d_in[0];
  const float* W  = (const float*)d_in[1];
  const float* bb = (const float*)d_in[2];
  const float* rW = (const float*)d_in[3];
  const float* rb = (const float*)d_in[4];
  const float* A  = (const float*)d_in[5];
  const float* Sa = (const float*)d_in[6];
  const float* B  = (const float*)d_in[7];
  const float* Sb = (const float*)d_in[8];
  float* out = (float*)d_out;

  char* ws = (char*)d_ws;
  float* gate  = (float*)ws;                            // 16384*8*4   = 512 KB
  bf16*  Acat  = (bf16*)(ws + (512 << 10));             // 256*1024*2  = 512 KB
  bf16*  BcatT = (bf16*)(ws + (1024 << 10));            // 1024*256*2  = 512 KB
  bf16*  Wb    = (bf16*)(ws + (1536 << 10));            // 1024*1024*2 = 2 MB
  bf16*  hg    = (bf16*)(ws + (3584 << 10));            // 16384*256*2 = 8 MB
  bf16*  xb    = (bf16*)(ws + (11776 << 10));           // 16384*1024*2 = 32 MB

  cvt_kernel<<<2048, 256, 0, stream>>>(x, xb, TT * DIN / 4);
  cvt_kernel<<<512, 256, 0, stream>>>(W, Wb, DOUT * DIN / 4);
  prep_kernel<<<512, 256, 0, stream>>>(A, Sa, B, Sb, Acat, BcatT);
  router_kernel<<<TT, 64, 0, stream>>>(xb, rW, rb, gate);
  gemm1_kernel<<<dim3(TT / 128, KCAT / 64), 256, 0, stream>>>(xb, Acat, gate, hg);
  gemm2_kernel<<<dim3(TT / 128, DOUT / 128), 256, 0, stream>>>(xb, Wb, bb, hg, BcatT, out);
}

// Round 4
// 217.368 us; speedup vs baseline: 1.1447x; 1.1447x over previous
//
#include <hip/hip_runtime.h>
#include <hip/hip_bf16.h>
#include <math.h>

// Problem constants
#define TT   16384   // tokens = 8*2048
#define DIN  1024
#define DOUT 1024
#define NEXP 8
#define RANK 32
#define KCAT 256     // NEXP*RANK

using bf16 = __hip_bfloat16;
typedef __attribute__((ext_vector_type(8))) short short8;
typedef __attribute__((ext_vector_type(4))) short short4v;
typedef __attribute__((ext_vector_type(4))) float f32x4;

static __device__ __forceinline__ float b2f(bf16 v) { return __bfloat162float(v); }
static __device__ __forceinline__ bf16  f2b(float v) { return __float2bfloat16(v); }

// async global->LDS, 16B per lane; LDS dest is wave-uniform base (+lane*16 by HW)
static __device__ __forceinline__ void load_lds16(const bf16* g, bf16* l) {
  __builtin_amdgcn_global_load_lds(
      (const __attribute__((address_space(1))) void*)g,
      (__attribute__((address_space(3))) void*)l, 16, 0, 0);
}

// Stage one 8-row group (row = 64 bf16 = 128B) of a [rows][64] bf16 LDS tile with
// XOR swizzle: physical chunk p (16B units) at row r holds logical chunk p^(r&7).
// LDS dest is linear (gload_lds requirement); the SOURCE address is pre-swizzled
// with the same involution (rule 21 / m173 pattern).
static __device__ __forceinline__ void stage_swz(const bf16* gRowBase, size_t lda,
                                                 bf16* ldsRowBase, int lane) {
  const int r = lane >> 3;                 // 0..7 within the 8-row group
  const int c = (lane & 7) ^ r;            // logical chunk for this lane's 16B slot
  load_lds16(gRowBase + (size_t)r * lda + c * 8, ldsRowBase);
}

// ---------------- cvt: f32 -> bf16, vectorized (for W) ----------------
__global__ __launch_bounds__(256) void cvt_kernel(const float* __restrict__ in,
                                                  bf16* __restrict__ out, int n4) {
  for (int i = blockIdx.x * blockDim.x + threadIdx.x; i < n4;
       i += gridDim.x * blockDim.x) {
    float4 v = ((const float4*)in)[i];
    union { short4v s; bf16 b[4]; } u;
    u.b[0] = f2b(v.x); u.b[1] = f2b(v.y); u.b[2] = f2b(v.z); u.b[3] = f2b(v.w);
    ((short4v*)out)[i] = u.s;
  }
}

// ---------------- prep: A_cat [256][1024] bf16, B_catT [1024][256] bf16 ----------------
__global__ __launch_bounds__(256) void prep_kernel(const float* __restrict__ A,
                                                   const float* __restrict__ Sa,
                                                   const float* __restrict__ B,
                                                   const float* __restrict__ Sb,
                                                   bf16* __restrict__ Acat,
                                                   bf16* __restrict__ BcatT) {
  const int n = NEXP * RANK * DIN; // 262144
  for (int idx = blockIdx.x * blockDim.x + threadIdx.x; idx < n;
       idx += gridDim.x * blockDim.x) {
    float a = A[idx];
    float s = Sa[idx];
    Acat[idx] = f2b(a * (1.0f / (1.0f + __expf(-s))));
    int o = idx >> 8;        // 0..1023
    int j = idx & 255;       // 0..255
    int e = j >> 5, r = j & 31;
    int src = e * (DOUT * RANK) + o * RANK + r;
    float bb = B[src];
    float sb = Sb[src];
    BcatT[idx] = f2b(bb * (1.0f / (1.0f + __expf(-sb))));
  }
}

// ---------------- fused cvt(x)+router: xb bf16 + gate [TT][8] f32 ----------------
// 4 waves/block, one token per wave. Router logits computed in full f32.
__global__ __launch_bounds__(256) void cvtrouter_kernel(const float* __restrict__ x,
                                                        const float* __restrict__ rW,
                                                        const float* __restrict__ rb,
                                                        bf16* __restrict__ xb,
                                                        float* __restrict__ gate) {
  const int wid = threadIdx.x >> 6, lane = threadIdx.x & 63;
  const int t = blockIdx.x * 4 + wid;
  const float* xrow = x + (size_t)t * DIN;
  bf16* xbrow = xb + (size_t)t * DIN;

  float xv[16];
  #pragma unroll
  for (int q = 0; q < 4; ++q) {
    float4 v = *(const float4*)&xrow[q * 256 + lane * 4];
    xv[q * 4 + 0] = v.x; xv[q * 4 + 1] = v.y; xv[q * 4 + 2] = v.z; xv[q * 4 + 3] = v.w;
    union { short4v s; bf16 b[4]; } u;
    u.b[0] = f2b(v.x); u.b[1] = f2b(v.y); u.b[2] = f2b(v.z); u.b[3] = f2b(v.w);
    *(short4v*)&xbrow[q * 256 + lane * 4] = u.s;
  }

  float acc[NEXP] = {};
  #pragma unroll
  for (int e = 0; e < NEXP; ++e) {
    #pragma unroll
    for (int q = 0; q < 4; ++q) {
      float4 w = *(const float4*)&rW[e * DIN + q * 256 + lane * 4];
      acc[e] += xv[q * 4 + 0] * w.x + xv[q * 4 + 1] * w.y +
                xv[q * 4 + 2] * w.z + xv[q * 4 + 3] * w.w;
    }
  }
  #pragma unroll
  for (int e = 0; e < NEXP; ++e) {
    #pragma unroll
    for (int off = 32; off > 0; off >>= 1)
      acc[e] += __shfl_xor(acc[e], off);
  }
  if (lane == 0) {
    float lg[NEXP];
    float mx = -1e30f;
    #pragma unroll
    for (int e = 0; e < NEXP; ++e) { lg[e] = acc[e] + rb[e]; mx = fmaxf(mx, lg[e]); }
    float se = 0.f;
    #pragma unroll
    for (int e = 0; e < NEXP; ++e) { lg[e] = __expf(lg[e] - mx); se += lg[e]; }
    float inv = 1.0f / se;
    int i1 = 0;
    #pragma unroll
    for (int e = 1; e < NEXP; ++e) if (lg[e] > lg[i1]) i1 = e;
    int i2 = (i1 == 0) ? 1 : 0;
    #pragma unroll
    for (int e = 0; e < NEXP; ++e) if (e != i1 && lg[e] > lg[i2]) i2 = e;
    #pragma unroll
    for (int e = 0; e < NEXP; ++e)
      gate[(size_t)t * NEXP + e] = (e == i1 || e == i2) ? lg[e] * inv : 0.0f;
  }
}

// ---------------- gemm1: hg[t][j] = gate[t][j/32] * sum_d xb[t,d]*Acat[j,d] ----------------
// BM=128, BN=64, BK=64; 4 waves 2x2; wave tile 64x32; swizzled LDS
__global__ __launch_bounds__(256) void gemm1_kernel(const bf16* __restrict__ xb,
                                                    const bf16* __restrict__ Acat,
                                                    const float* __restrict__ gate,
                                                    bf16* __restrict__ hg) {
  __shared__ alignas(16) bf16 As[128][64];
  __shared__ alignas(16) bf16 Bs[64][64];
  const int tid = threadIdx.x, wid = tid >> 6, lane = tid & 63;
  const int wr = wid >> 1, wc = wid & 1;
  const int tileRow = blockIdx.x * 128, tileCol = blockIdx.y * 64;
  f32x4 acc[4][2] = {};

  for (int kt = 0; kt < DIN / 64; ++kt) {
    const int k0 = kt * 64;
    #pragma unroll
    for (int i = 0; i < 4; ++i) {
      int br = wid * 32 + i * 8;
      stage_swz(xb + (size_t)(tileRow + br) * DIN + k0, DIN, &As[br][0], lane);
    }
    #pragma unroll
    for (int i = 0; i < 2; ++i) {
      int br = wid * 16 + i * 8;
      stage_swz(Acat + (size_t)(tileCol + br) * DIN + k0, DIN, &Bs[br][0], lane);
    }
    __syncthreads();
    #pragma unroll
    for (int ks = 0; ks < 2; ++ks) {
      const int pcA = ((ks * 4) + (lane >> 4)) ^ (lane & 7); // phys chunk (row&7 == lane&7)
      short8 a[4], b[2];
      #pragma unroll
      for (int m = 0; m < 4; ++m)
        a[m] = *(const short8*)&As[wr * 64 + m * 16 + (lane & 15)][pcA * 8];
      #pragma unroll
      for (int n = 0; n < 2; ++n)
        b[n] = *(const short8*)&Bs[wc * 32 + n * 16 + (lane & 15)][pcA * 8];
      #pragma unroll
      for (int m = 0; m < 4; ++m)
        #pragma unroll
        for (int n = 0; n < 2; ++n)
          acc[m][n] = __builtin_amdgcn_mfma_f32_16x16x32_bf16(a[m], b[n], acc[m][n], 0, 0, 0);
    }
    __syncthreads();
  }

  #pragma unroll
  for (int n = 0; n < 2; ++n) {
    int j = tileCol + wc * 32 + n * 16 + (lane & 15);
    int e = j >> 5;
    #pragma unroll
    for (int m = 0; m < 4; ++m) {
      int row0 = tileRow + wr * 64 + m * 16 + (lane >> 4) * 4;
      #pragma unroll
      for (int r = 0; r < 4; ++r) {
        float g = gate[(size_t)(row0 + r) * NEXP + e];
        hg[(size_t)(row0 + r) * KCAT + j] = f2b(acc[m][n][r] * g);
      }
    }
  }
}

// ---------------- gemm2: y = xb@Wb^T + hg@BcatT^T + b  (K = 1024 | 256) ----------------
// BM=128, BN=128, BK=64; 4 waves 2x2; wave tile 64x64; swizzled LDS
__global__ __launch_bounds__(256) void gemm2_kernel(const bf16* __restrict__ xb,
                                                    const bf16* __restrict__ Wb,
                                                    const float* __restrict__ bias,
                                                    const bf16* __restrict__ hg,
                                                    const bf16* __restrict__ BcatT,
                                                    float* __restrict__ out) {
  __shared__ alignas(16) bf16 As[128][64];
  __shared__ alignas(16) bf16 Bs[128][64];
  const int tid = threadIdx.x, wid = tid >> 6, lane = tid & 63;
  const int wr = wid >> 1, wc = wid & 1;
  const int tileRow = blockIdx.x * 128, tileCol = blockIdx.y * 128;
  f32x4 acc[4][4] = {};

  auto tile_step = [&](const bf16* aptr, const bf16* bptr, size_t lda, int k0) {
    #pragma unroll
    for (int i = 0; i < 4; ++i) {
      int br = wid * 32 + i * 8;
      stage_swz(aptr + (size_t)(tileRow + br) * lda + k0, lda, &As[br][0], lane);
      stage_swz(bptr + (size_t)(tileCol + br) * lda + k0, lda, &Bs[br][0], lane);
    }
    __syncthreads();
    #pragma unroll
    for (int ks = 0; ks < 2; ++ks) {
      const int pc = ((ks * 4) + (lane >> 4)) ^ (lane & 7);
      short8 a[4], b[4];
      #pragma unroll
      for (int m = 0; m < 4; ++m)
        a[m] = *(const short8*)&As[wr * 64 + m * 16 + (lane & 15)][pc * 8];
      #pragma unroll
      for (int n = 0; n < 4; ++n)
        b[n] = *(const short8*)&Bs[wc * 64 + n * 16 + (lane & 15)][pc * 8];
      #pragma unroll
      for (int m = 0; m < 4; ++m)
        #pragma unroll
        for (int n = 0; n < 4; ++n)
          acc[m][n] = __builtin_amdgcn_mfma_f32_16x16x32_bf16(a[m], b[n], acc[m][n], 0, 0, 0);
    }
    __syncthreads();
  };

  for (int kt = 0; kt < DIN / 64; ++kt)
    tile_step(xb, Wb, DIN, kt * 64);
  for (int kt = 0; kt < KCAT / 64; ++kt)
    tile_step(hg, BcatT, KCAT, kt * 64);

  #pragma unroll
  for (int n = 0; n < 4; ++n) {
    int col = tileCol + wc * 64 + n * 16 + (lane & 15);
    float bb = bias[col];
    #pragma unroll
    for (int m = 0; m < 4; ++m) {
      int row0 = tileRow + wr * 64 + m * 16 + (lane >> 4) * 4;
      #pragma unroll
      for (int r = 0; r < 4; ++r)
        out[(size_t)(row0 + r) * DOUT + col] = acc[m][n][r] + bb;
    }
  }
}

extern "C" void kernel_launch(void* const* d_in, const int* in_sizes, int n_in,
                              void* d_out, int out_size, void* d_ws, size_t ws_size,
                              hipStream_t stream) {
  const float* x  = (const float*)d_in[0];
  const float* W  = (const float*)d_in[1];
  const float* bb = (const float*)d_in[2];
  const float* rW = (const float*)d_in[3];
  const float* rb = (const float*)d_in[4];
  const float* A  = (const float*)d_in[5];
  const float* Sa = (const float*)d_in[6];
  const float* B  = (const float*)d_in[7];
  const float* Sb = (const float*)d_in[8];
  float* out = (float*)d_out;

  char* ws = (char*)d_ws;
  float* gate  = (float*)ws;                            // 16384*8*4   = 512 KB
  bf16*  Acat  = (bf16*)(ws + (512 << 10));             // 256*1024*2  = 512 KB
  bf16*  BcatT = (bf16*)(ws + (1024 << 10));            // 1024*256*2  = 512 KB
  bf16*  Wb    = (bf16*)(ws + (1536 << 10));            // 1024*1024*2 = 2 MB
  bf16*  hg    = (bf16*)(ws + (3584 << 10));            // 16384*256*2 = 8 MB
  bf16*  xb    = (bf16*)(ws + (11776 << 10));           // 16384*1024*2 = 32 MB

  cvt_kernel<<<512, 256, 0, stream>>>(W, Wb, DOUT * DIN / 4);
  prep_kernel<<<512, 256, 0, stream>>>(A, Sa, B, Sb, Acat, BcatT);
  cvtrouter_kernel<<<TT / 4, 256, 0, stream>>>(x, rW, rb, xb, gate);
  gemm1_kernel<<<dim3(TT / 128, KCAT / 64), 256, 0, stream>>>(xb, Acat, gate, hg);
  gemm2_kernel<<<dim3(TT / 128, DOUT / 128), 256, 0, stream>>>(xb, Wb, bb, hg, BcatT, out);
}

// Round 8
// 211.554 us; speedup vs baseline: 1.1761x; 1.0275x over previous
//
#include <hip/hip_runtime.h>
#include <hip/hip_bf16.h>
#include <math.h>

// Problem constants
#define TT   16384   // tokens = 8*2048
#define DIN  1024
#define DOUT 1024
#define NEXP 8
#define RANK 32
#define KCAT 256     // NEXP*RANK

using bf16 = __hip_bfloat16;
typedef __attribute__((ext_vector_type(8))) short short8;
typedef __attribute__((ext_vector_type(4))) short short4v;
typedef __attribute__((ext_vector_type(4))) float f32x4;

static __device__ __forceinline__ float b2f(bf16 v) { return __bfloat162float(v); }
static __device__ __forceinline__ bf16  f2b(float v) { return __float2bfloat16(v); }

// async global->LDS, 16B per lane; LDS dest is wave-uniform base (+lane*16 by HW)
static __device__ __forceinline__ void load_lds16(const bf16* g, bf16* l) {
  __builtin_amdgcn_global_load_lds(
      (const __attribute__((address_space(1))) void*)g,
      (__attribute__((address_space(3))) void*)l, 16, 0, 0);
}

// Stage one 8-row group (row = 64 bf16 = 128B) of a [rows][64] bf16 LDS tile with
// XOR swizzle: physical chunk p (16B units) at row r holds logical chunk p^(r&7).
// LDS dest is linear (gload_lds requirement); the SOURCE address is pre-swizzled
// with the same involution (rule 21 / m173 pattern). R4-verified: 0 bank conflicts.
static __device__ __forceinline__ void stage_swz(const bf16* gRowBase, size_t lda,
                                                 bf16* ldsRowBase, int lane) {
  const int r = lane >> 3;                 // 0..7 within the 8-row group
  const int c = (lane & 7) ^ r;            // logical chunk for this lane's 16B slot
  load_lds16(gRowBase + (size_t)r * lda + c * 8, ldsRowBase);
}

// ---------------- cvt: f32 -> bf16, vectorized (for W) ----------------
__global__ __launch_bounds__(256) void cvt_kernel(const float* __restrict__ in,
                                                  bf16* __restrict__ out, int n4) {
  for (int i = blockIdx.x * blockDim.x + threadIdx.x; i < n4;
       i += gridDim.x * blockDim.x) {
    float4 v = ((const float4*)in)[i];
    union { short4v s; bf16 b[4]; } u;
    u.b[0] = f2b(v.x); u.b[1] = f2b(v.y); u.b[2] = f2b(v.z); u.b[3] = f2b(v.w);
    ((short4v*)out)[i] = u.s;
  }
}

// ---------------- prep: A_cat [256][1024] bf16, B_catT [1024][256] bf16 ----------------
__global__ __launch_bounds__(256) void prep_kernel(const float* __restrict__ A,
                                                   const float* __restrict__ Sa,
                                                   const float* __restrict__ B,
                                                   const float* __restrict__ Sb,
                                                   bf16* __restrict__ Acat,
                                                   bf16* __restrict__ BcatT) {
  const int n = NEXP * RANK * DIN; // 262144
  for (int idx = blockIdx.x * blockDim.x + threadIdx.x; idx < n;
       idx += gridDim.x * blockDim.x) {
    float a = A[idx];
    float s = Sa[idx];
    Acat[idx] = f2b(a * (1.0f / (1.0f + __expf(-s))));
    int o = idx >> 8;        // 0..1023
    int j = idx & 255;       // 0..255
    int e = j >> 5, r = j & 31;
    int src = e * (DOUT * RANK) + o * RANK + r;
    float bb = B[src];
    float sb = Sb[src];
    BcatT[idx] = f2b(bb * (1.0f / (1.0f + __expf(-sb))));
  }
}

// ---------------- fused cvt(x)+router: xb bf16 + gate [TT][8] f32 ----------------
__global__ __launch_bounds__(256) void cvtrouter_kernel(const float* __restrict__ x,
                                                        const float* __restrict__ rW,
                                                        const float* __restrict__ rb,
                                                        bf16* __restrict__ xb,
                                                        float* __restrict__ gate) {
  const int wid = threadIdx.x >> 6, lane = threadIdx.x & 63;
  const int t = blockIdx.x * 4 + wid;
  const float* xrow = x + (size_t)t * DIN;
  bf16* xbrow = xb + (size_t)t * DIN;

  float xv[16];
  #pragma unroll
  for (int q = 0; q < 4; ++q) {
    float4 v = *(const float4*)&xrow[q * 256 + lane * 4];
    xv[q * 4 + 0] = v.x; xv[q * 4 + 1] = v.y; xv[q * 4 + 2] = v.z; xv[q * 4 + 3] = v.w;
    union { short4v s; bf16 b[4]; } u;
    u.b[0] = f2b(v.x); u.b[1] = f2b(v.y); u.b[2] = f2b(v.z); u.b[3] = f2b(v.w);
    *(short4v*)&xbrow[q * 256 + lane * 4] = u.s;
  }

  float acc[NEXP] = {};
  #pragma unroll
  for (int e = 0; e < NEXP; ++e) {
    #pragma unroll
    for (int q = 0; q < 4; ++q) {
      float4 w = *(const float4*)&rW[e * DIN + q * 256 + lane * 4];
      acc[e] += xv[q * 4 + 0] * w.x + xv[q * 4 + 1] * w.y +
                xv[q * 4 + 2] * w.z + xv[q * 4 + 3] * w.w;
    }
  }
  #pragma unroll
  for (int e = 0; e < NEXP; ++e) {
    #pragma unroll
    for (int off = 32; off > 0; off >>= 1)
      acc[e] += __shfl_xor(acc[e], off);
  }
  if (lane == 0) {
    float lg[NEXP];
    float mx = -1e30f;
    #pragma unroll
    for (int e = 0; e < NEXP; ++e) { lg[e] = acc[e] + rb[e]; mx = fmaxf(mx, lg[e]); }
    float se = 0.f;
    #pragma unroll
    for (int e = 0; e < NEXP; ++e) { lg[e] = __expf(lg[e] - mx); se += lg[e]; }
    float inv = 1.0f / se;
    int i1 = 0;
    #pragma unroll
    for (int e = 1; e < NEXP; ++e) if (lg[e] > lg[i1]) i1 = e;
    int i2 = (i1 == 0) ? 1 : 0;
    #pragma unroll
    for (int e = 0; e < NEXP; ++e) if (e != i1 && lg[e] > lg[i2]) i2 = e;
    #pragma unroll
    for (int e = 0; e < NEXP; ++e)
      gate[(size_t)t * NEXP + e] = (e == i1 || e == i2) ? lg[e] * inv : 0.0f;
  }
}

// ---------------- gemm1: hg[t][j] = gate[t][j/32] * sum_d xb[t,d]*Acat[j,d] ----------------
// BM=128, BN=64, BK=64; 4 waves 2x2; wave tile 64x32; swizzled LDS (unchanged from R4)
__global__ __launch_bounds__(256) void gemm1_kernel(const bf16* __restrict__ xb,
                                                    const bf16* __restrict__ Acat,
                                                    const float* __restrict__ gate,
                                                    bf16* __restrict__ hg) {
  __shared__ alignas(16) bf16 As[128][64];
  __shared__ alignas(16) bf16 Bs[64][64];
  const int tid = threadIdx.x, wid = tid >> 6, lane = tid & 63;
  const int wr = wid >> 1, wc = wid & 1;
  const int tileRow = blockIdx.x * 128, tileCol = blockIdx.y * 64;
  f32x4 acc[4][2] = {};

  for (int kt = 0; kt < DIN / 64; ++kt) {
    const int k0 = kt * 64;
    #pragma unroll
    for (int i = 0; i < 4; ++i) {
      int br = wid * 32 + i * 8;
      stage_swz(xb + (size_t)(tileRow + br) * DIN + k0, DIN, &As[br][0], lane);
    }
    #pragma unroll
    for (int i = 0; i < 2; ++i) {
      int br = wid * 16 + i * 8;
      stage_swz(Acat + (size_t)(tileCol + br) * DIN + k0, DIN, &Bs[br][0], lane);
    }
    __syncthreads();
    #pragma unroll
    for (int ks = 0; ks < 2; ++ks) {
      const int pcA = ((ks * 4) + (lane >> 4)) ^ (lane & 7);
      short8 a[4], b[2];
      #pragma unroll
      for (int m = 0; m < 4; ++m)
        a[m] = *(const short8*)&As[wr * 64 + m * 16 + (lane & 15)][pcA * 8];
      #pragma unroll
      for (int n = 0; n < 2; ++n)
        b[n] = *(const short8*)&Bs[wc * 32 + n * 16 + (lane & 15)][pcA * 8];
      #pragma unroll
      for (int m = 0; m < 4; ++m)
        #pragma unroll
        for (int n = 0; n < 2; ++n)
          acc[m][n] = __builtin_amdgcn_mfma_f32_16x16x32_bf16(a[m], b[n], acc[m][n], 0, 0, 0);
    }
    __syncthreads();
  }

  #pragma unroll
  for (int n = 0; n < 2; ++n) {
    int j = tileCol + wc * 32 + n * 16 + (lane & 15);
    int e = j >> 5;
    #pragma unroll
    for (int m = 0; m < 4; ++m) {
      int row0 = tileRow + wr * 64 + m * 16 + (lane >> 4) * 4;
      #pragma unroll
      for (int r = 0; r < 4; ++r) {
        float g = gate[(size_t)(row0 + r) * NEXP + e];
        hg[(size_t)(row0 + r) * KCAT + j] = f2b(acc[m][n][r] * g);
      }
    }
  }
}

// ---------------- gemm2: y = xb@Wb^T + hg@BcatT^T + b  (concat K = 1024 | 256) ----------------
// 256x256 tile, BK=64, 8 waves (2Mx4N), 8-phase-style schedule (4 phases/K-tile),
// double-buffered LDS, counted vmcnt (never 0 in steady state), T2 swizzle, T5 setprio.
#define KT2 20
#define KSW 16
__global__ __launch_bounds__(512, 2) void gemm2_kernel(const bf16* __restrict__ xb,
                                                       const bf16* __restrict__ Wb,
                                                       const float* __restrict__ bias,
                                                       const bf16* __restrict__ hg,
                                                       const bf16* __restrict__ BcatT,
                                                       float* __restrict__ out) {
  __shared__ alignas(16) bf16 As[2][256][64];   // 64 KiB
  __shared__ alignas(16) bf16 Bs[2][256][64];   // 64 KiB
  const int tid = threadIdx.x, wid = tid >> 6, lane = tid & 63;
  const int wm = wid >> 2, wn = wid & 3;        // 2 x 4 wave grid
  const int tileRow = blockIdx.x * 256, tileCol = blockIdx.y * 256;
  f32x4 acc[8][4] = {};

  // stage one half (h=0: rows 0-127, h=1: rows 128-255) of tile t (2 gload/thread)
  auto stageA = [&](int t, int h) {
    const bf16* p; size_t lda; int k0;
    if (t < KSW) { p = xb + (size_t)tileRow * DIN;  lda = DIN;  k0 = t * 64; }
    else         { p = hg + (size_t)tileRow * KCAT; lda = KCAT; k0 = (t - KSW) * 64; }
    const int buf = t & 1;
    #pragma unroll
    for (int rnd = 0; rnd < 2; ++rnd) {
      int rb = h * 128 + rnd * 64 + wid * 8;
      stage_swz(p + (size_t)rb * lda + k0, lda, &As[buf][rb][0], lane);
    }
  };
  auto stageB = [&](int t, int h) {
    const bf16* p; size_t lda; int k0;
    if (t < KSW) { p = Wb + (size_t)tileCol * DIN;     lda = DIN;  k0 = t * 64; }
    else         { p = BcatT + (size_t)tileCol * KCAT; lda = KCAT; k0 = (t - KSW) * 64; }
    const int buf = t & 1;
    #pragma unroll
    for (int rnd = 0; rnd < 2; ++rnd) {
      int rb = h * 128 + rnd * 64 + wid * 8;
      stage_swz(p + (size_t)rb * lda + k0, lda, &Bs[buf][rb][0], lane);
    }
  };
  // fragment reads (swizzled): row&7 == lane&7 since frag rows step by 16
  auto ldA = [&](int buf, int mf, int ks) -> short8 {
    int row = wm * 128 + mf * 16 + (lane & 15);
    int pc = ((ks * 4) + (lane >> 4)) ^ (lane & 7);
    return *(const short8*)&As[buf][row][pc * 8];
  };
  auto ldB = [&](int buf, int nf, int ks) -> short8 {
    int row = wn * 64 + nf * 16 + (lane & 15);
    int pc = ((ks * 4) + (lane >> 4)) ^ (lane & 7);
    return *(const short8*)&Bs[buf][row][pc * 8];
  };

  // ---- prologue: tile0 (4 halves) + tile1 A-halves; wait leaves A(1) in flight ----
  stageA(0, 0); stageA(0, 1); stageB(0, 0); stageB(0, 1);
  stageA(1, 0); stageA(1, 1);
  asm volatile("s_waitcnt vmcnt(4)" ::: "memory");
  __builtin_amdgcn_s_barrier();

  for (int t = 0; t < KT2; ++t) {
    const int cur = t & 1;
    short8 af0[4][2], af1[4][2], bf[2][2];

    // ---- phase 0: quadrant (mh0, nh0); issue B0(t+1) -> buf[nxt] ----
    #pragma unroll
    for (int m = 0; m < 4; ++m)
      #pragma unroll
      for (int ks = 0; ks < 2; ++ks) af0[m][ks] = ldA(cur, m, ks);
    #pragma unroll
    for (int n = 0; n < 2; ++n)
      #pragma unroll
      for (int ks = 0; ks < 2; ++ks) bf[n][ks] = ldB(cur, n, ks);
    if (t + 1 < KT2) stageB(t + 1, 0);
    __builtin_amdgcn_s_barrier();
    asm volatile("s_waitcnt lgkmcnt(0)" ::: "memory");
    __builtin_amdgcn_sched_barrier(0);
    __builtin_amdgcn_s_setprio(1);
    #pragma unroll
    for (int m = 0; m < 4; ++m)
      #pragma unroll
      for (int n = 0; n < 2; ++n)
        #pragma unroll
        for (int ks = 0; ks < 2; ++ks)
          acc[m][n] = __builtin_amdgcn_mfma_f32_16x16x32_bf16(af0[m][ks], bf[n][ks], acc[m][n], 0, 0, 0);
    __builtin_amdgcn_s_setprio(0);
    __builtin_amdgcn_s_barrier();

    // ---- phase 1: quadrant (mh0, nh1); issue B1(t+1) ----
    #pragma unroll
    for (int n = 0; n < 2; ++n)
      #pragma unroll
      for (int ks = 0; ks < 2; ++ks) bf[n][ks] = ldB(cur, 2 + n, ks);
    if (t + 1 < KT2) stageB(t + 1, 1);
    __builtin_amdgcn_s_barrier();
    asm volatile("s_waitcnt lgkmcnt(0)" ::: "memory");
    __builtin_amdgcn_sched_barrier(0);
    __builtin_amdgcn_s_setprio(1);
    #pragma unroll
    for (int m = 0; m < 4; ++m)
      #pragma unroll
      for (int n = 0; n < 2; ++n)
        #pragma unroll
        for (int ks = 0; ks < 2; ++ks)
          acc[m][2 + n] = __builtin_amdgcn_mfma_f32_16x16x32_bf16(af0[m][ks], bf[n][ks], acc[m][2 + n], 0, 0, 0);
    __builtin_amdgcn_s_setprio(0);
    __builtin_amdgcn_s_barrier();

    // ---- phase 2: quadrant (mh1, nh0) ----
    #pragma unroll
    for (int m = 0; m < 4; ++m)
      #pragma unroll
      for (int ks = 0; ks < 2; ++ks) af1[m][ks] = ldA(cur, 4 + m, ks);
    #pragma unroll
    for (int n = 0; n < 2; ++n)
      #pragma unroll
      for (int ks = 0; ks < 2; ++ks) bf[n][ks] = ldB(cur, n, ks);
    __builtin_amdgcn_s_barrier();
    asm volatile("s_waitcnt lgkmcnt(0)" ::: "memory");
    __builtin_amdgcn_sched_barrier(0);
    __builtin_amdgcn_s_setprio(1);
    #pragma unroll
    for (int m = 0; m < 4; ++m)
      #pragma unroll
      for (int n = 0; n < 2; ++n)
        #pragma unroll
        for (int ks = 0; ks < 2; ++ks)
          acc[4 + m][n] = __builtin_amdgcn_mfma_f32_16x16x32_bf16(af1[m][ks], bf[n][ks], acc[4 + m][n], 0, 0, 0);
    __builtin_amdgcn_s_setprio(0);
    __builtin_amdgcn_s_barrier();

    // ---- phase 3: quadrant (mh1, nh1); issue A(t+2) -> buf[cur] (A-halves of cur
    // are dead after phase-2's post-barrier); counted boundary wait ----
    #pragma unroll
    for (int n = 0; n < 2; ++n)
      #pragma unroll
      for (int ks = 0; ks < 2; ++ks) bf[n][ks] = ldB(cur, 2 + n, ks);
    if (t + 2 < KT2) { stageA(t + 2, 0); stageA(t + 2, 1); }
    if (t + 1 < KT2) {
      if (t + 2 < KT2) asm volatile("s_waitcnt vmcnt(4)" ::: "memory"); // leaves A(t+2) in flight
      else             asm volatile("s_waitcnt vmcnt(0)" ::: "memory"); // tail only
    }
    __builtin_amdgcn_s_barrier();
    asm volatile("s_waitcnt lgkmcnt(0)" ::: "memory");
    __builtin_amdgcn_sched_barrier(0);
    __builtin_amdgcn_s_setprio(1);
    #pragma unroll
    for (int m = 0; m < 4; ++m)
      #pragma unroll
      for (int n = 0; n < 2; ++n)
        #pragma unroll
        for (int ks = 0; ks < 2; ++ks)
          acc[4 + m][2 + n] = __builtin_amdgcn_mfma_f32_16x16x32_bf16(af1[m][ks], bf[n][ks], acc[4 + m][2 + n], 0, 0, 0);
    __builtin_amdgcn_s_setprio(0);
    __builtin_amdgcn_s_barrier();
  }

  // ---- epilogue ----
  #pragma unroll
  for (int n = 0; n < 4; ++n) {
    int col = tileCol + wn * 64 + n * 16 + (lane & 15);
    float bb = bias[col];
    #pragma unroll
    for (int m = 0; m < 8; ++m) {
      int row0 = tileRow + wm * 128 + m * 16 + (lane >> 4) * 4;
      #pragma unroll
      for (int r = 0; r < 4; ++r)
        out[(size_t)(row0 + r) * DOUT + col] = acc[m][n][r] + bb;
    }
  }
}

extern "C" void kernel_launch(void* const* d_in, const int* in_sizes, int n_in,
                              void* d_out, int out_size, void* d_ws, size_t ws_size,
                              hipStream_t stream) {
  const float* x  = (const float*)d_in[0];
  const float* W  = (const float*)d_in[1];
  const float* bb = (const float*)d_in[2];
  const float* rW = (const float*)d_in[3];
  const float* rb = (const float*)d_in[4];
  const float* A  = (const float*)d_in[5];
  const float* Sa = (const float*)d_in[6];
  const float* B  = (const float*)d_in[7];
  const float* Sb = (const float*)d_in[8];
  float* out = (float*)d_out;

  char* ws = (char*)d_ws;
  float* gate  = (float*)ws;                            // 16384*8*4   = 512 KB
  bf16*  Acat  = (bf16*)(ws + (512 << 10));             // 256*1024*2  = 512 KB
  bf16*  BcatT = (bf16*)(ws + (1024 << 10));            // 1024*256*2  = 512 KB
  bf16*  Wb    = (bf16*)(ws + (1536 << 10));            // 1024*1024*2 = 2 MB
  bf16*  hg    = (bf16*)(ws + (3584 << 10));             // 16384*256*2 = 8 MB
  bf16*  xb    = (bf16*)(ws + (11776 << 10));            // 16384*1024*2 = 32 MB

  cvt_kernel<<<512, 256, 0, stream>>>(W, Wb, DOUT * DIN / 4);
  prep_kernel<<<512, 256, 0, stream>>>(A, Sa, B, Sb, Acat, BcatT);
  cvtrouter_kernel<<<TT / 4, 256, 0, stream>>>(x, rW, rb, xb, gate);
  gemm1_kernel<<<dim3(TT / 128, KCAT / 64), 256, 0, stream>>>(xb, Acat, gate, hg);
  gemm2_kernel<<<dim3(TT / 256, DOUT / 256), 512, 0, stream>>>(xb, Wb, bb, hg, BcatT, out);
}

// Round 10
// 210.097 us; speedup vs baseline: 1.1843x; 1.0069x over previous
//
#include <hip/hip_runtime.h>
#include <hip/hip_bf16.h>
#include <math.h>

// Problem constants
#define TT   16384   // tokens = 8*2048
#define DIN  1024
#define DOUT 1024
#define NEXP 8
#define RANK 32
#define KCAT 256     // NEXP*RANK

using bf16 = __hip_bfloat16;
typedef __attribute__((ext_vector_type(8))) short short8;
typedef __attribute__((ext_vector_type(4))) short short4v;
typedef __attribute__((ext_vector_type(4))) float f32x4;

static __device__ __forceinline__ float b2f(bf16 v) { return __bfloat162float(v); }
static __device__ __forceinline__ bf16  f2b(float v) { return __float2bfloat16(v); }

// async global->LDS, 16B per lane; LDS dest is wave-uniform base (+lane*16 by HW)
static __device__ __forceinline__ void load_lds16(const bf16* g, bf16* l) {
  __builtin_amdgcn_global_load_lds(
      (const __attribute__((address_space(1))) void*)g,
      (__attribute__((address_space(3))) void*)l, 16, 0, 0);
}

// Stage one 8-row group (row = 64 bf16 = 128B) of a [rows][64] bf16 LDS tile with
// XOR swizzle: physical chunk p (16B units) at row r holds logical chunk p^(r&7).
// LDS dest is linear (gload_lds requirement); the SOURCE address is pre-swizzled
// with the same involution (rule 21 / m173 pattern). R4-verified: 0 bank conflicts.
static __device__ __forceinline__ void stage_swz(const bf16* gRowBase, size_t lda,
                                                 bf16* ldsRowBase, int lane) {
  const int r = lane >> 3;                 // 0..7 within the 8-row group
  const int c = (lane & 7) ^ r;            // logical chunk for this lane's 16B slot
  load_lds16(gRowBase + (size_t)r * lda + c * 8, ldsRowBase);
}

// ---------------- cvt: f32 -> bf16, vectorized (for W) ----------------
__global__ __launch_bounds__(256) void cvt_kernel(const float* __restrict__ in,
                                                  bf16* __restrict__ out, int n4) {
  for (int i = blockIdx.x * blockDim.x + threadIdx.x; i < n4;
       i += gridDim.x * blockDim.x) {
    float4 v = ((const float4*)in)[i];
    union { short4v s; bf16 b[4]; } u;
    u.b[0] = f2b(v.x); u.b[1] = f2b(v.y); u.b[2] = f2b(v.z); u.b[3] = f2b(v.w);
    ((short4v*)out)[i] = u.s;
  }
}

// ---------------- prep: A_cat [256][1024] bf16, B_catT [1024][256] bf16 ----------------
__global__ __launch_bounds__(256) void prep_kernel(const float* __restrict__ A,
                                                   const float* __restrict__ Sa,
                                                   const float* __restrict__ B,
                                                   const float* __restrict__ Sb,
                                                   bf16* __restrict__ Acat,
                                                   bf16* __restrict__ BcatT) {
  const int n = NEXP * RANK * DIN; // 262144
  for (int idx = blockIdx.x * blockDim.x + threadIdx.x; idx < n;
       idx += gridDim.x * blockDim.x) {
    float a = A[idx];
    float s = Sa[idx];
    Acat[idx] = f2b(a * (1.0f / (1.0f + __expf(-s))));
    int o = idx >> 8;        // 0..1023
    int j = idx & 255;       // 0..255
    int e = j >> 5, r = j & 31;
    int src = e * (DOUT * RANK) + o * RANK + r;
    float bb = B[src];
    float sb = Sb[src];
    BcatT[idx] = f2b(bb * (1.0f / (1.0f + __expf(-sb))));
  }
}

// ---------------- fused cvt(x)+router: xb bf16 + gate [TT][8] f32 ----------------
__global__ __launch_bounds__(256) void cvtrouter_kernel(const float* __restrict__ x,
                                                        const float* __restrict__ rW,
                                                        const float* __restrict__ rb,
                                                        bf16* __restrict__ xb,
                                                        float* __restrict__ gate) {
  const int wid = threadIdx.x >> 6, lane = threadIdx.x & 63;
  const int t = blockIdx.x * 4 + wid;
  const float* xrow = x + (size_t)t * DIN;
  bf16* xbrow = xb + (size_t)t * DIN;

  float xv[16];
  #pragma unroll
  for (int q = 0; q < 4; ++q) {
    float4 v = *(const float4*)&xrow[q * 256 + lane * 4];
    xv[q * 4 + 0] = v.x; xv[q * 4 + 1] = v.y; xv[q * 4 + 2] = v.z; xv[q * 4 + 3] = v.w;
    union { short4v s; bf16 b[4]; } u;
    u.b[0] = f2b(v.x); u.b[1] = f2b(v.y); u.b[2] = f2b(v.z); u.b[3] = f2b(v.w);
    *(short4v*)&xbrow[q * 256 + lane * 4] = u.s;
  }

  float acc[NEXP] = {};
  #pragma unroll
  for (int e = 0; e < NEXP; ++e) {
    #pragma unroll
    for (int q = 0; q < 4; ++q) {
      float4 w = *(const float4*)&rW[e * DIN + q * 256 + lane * 4];
      acc[e] += xv[q * 4 + 0] * w.x + xv[q * 4 + 1] * w.y +
                xv[q * 4 + 2] * w.z + xv[q * 4 + 3] * w.w;
    }
  }
  #pragma unroll
  for (int e = 0; e < NEXP; ++e) {
    #pragma unroll
    for (int off = 32; off > 0; off >>= 1)
      acc[e] += __shfl_xor(acc[e], off);
  }
  if (lane == 0) {
    float lg[NEXP];
    float mx = -1e30f;
    #pragma unroll
    for (int e = 0; e < NEXP; ++e) { lg[e] = acc[e] + rb[e]; mx = fmaxf(mx, lg[e]); }
    float se = 0.f;
    #pragma unroll
    for (int e = 0; e < NEXP; ++e) { lg[e] = __expf(lg[e] - mx); se += lg[e]; }
    float inv = 1.0f / se;
    int i1 = 0;
    #pragma unroll
    for (int e = 1; e < NEXP; ++e) if (lg[e] > lg[i1]) i1 = e;
    int i2 = (i1 == 0) ? 1 : 0;
    #pragma unroll
    for (int e = 0; e < NEXP; ++e) if (e != i1 && lg[e] > lg[i2]) i2 = e;
    #pragma unroll
    for (int e = 0; e < NEXP; ++e)
      gate[(size_t)t * NEXP + e] = (e == i1 || e == i2) ? lg[e] * inv : 0.0f;
  }
}

// ---------------- gemm1: hg[t][j] = gate[t][j/32] * sum_d xb[t,d]*Acat[j,d] ----------------
// BM=128, BN=64, BK=64; 4 waves 2x2; wave tile 64x32; swizzled LDS (unchanged)
__global__ __launch_bounds__(256) void gemm1_kernel(const bf16* __restrict__ xb,
                                                    const bf16* __restrict__ Acat,
                                                    const float* __restrict__ gate,
                                                    bf16* __restrict__ hg) {
  __shared__ alignas(16) bf16 As[128][64];
  __shared__ alignas(16) bf16 Bs[64][64];
  const int tid = threadIdx.x, wid = tid >> 6, lane = tid & 63;
  const int wr = wid >> 1, wc = wid & 1;
  const int tileRow = blockIdx.x * 128, tileCol = blockIdx.y * 64;
  f32x4 acc[4][2] = {};

  for (int kt = 0; kt < DIN / 64; ++kt) {
    const int k0 = kt * 64;
    #pragma unroll
    for (int i = 0; i < 4; ++i) {
      int br = wid * 32 + i * 8;
      stage_swz(xb + (size_t)(tileRow + br) * DIN + k0, DIN, &As[br][0], lane);
    }
    #pragma unroll
    for (int i = 0; i < 2; ++i) {
      int br = wid * 16 + i * 8;
      stage_swz(Acat + (size_t)(tileCol + br) * DIN + k0, DIN, &Bs[br][0], lane);
    }
    __syncthreads();
    #pragma unroll
    for (int ks = 0; ks < 2; ++ks) {
      const int pcA = ((ks * 4) + (lane >> 4)) ^ (lane & 7);
      short8 a[4], b[2];
      #pragma unroll
      for (int m = 0; m < 4; ++m)
        a[m] = *(const short8*)&As[wr * 64 + m * 16 + (lane & 15)][pcA * 8];
      #pragma unroll
      for (int n = 0; n < 2; ++n)
        b[n] = *(const short8*)&Bs[wc * 32 + n * 16 + (lane & 15)][pcA * 8];
      #pragma unroll
      for (int m = 0; m < 4; ++m)
        #pragma unroll
        for (int n = 0; n < 2; ++n)
          acc[m][n] = __builtin_amdgcn_mfma_f32_16x16x32_bf16(a[m], b[n], acc[m][n], 0, 0, 0);
    }
    __syncthreads();
  }

  #pragma unroll
  for (int n = 0; n < 2; ++n) {
    int j = tileCol + wc * 32 + n * 16 + (lane & 15);
    int e = j >> 5;
    #pragma unroll
    for (int m = 0; m < 4; ++m) {
      int row0 = tileRow + wr * 64 + m * 16 + (lane >> 4) * 4;
      #pragma unroll
      for (int r = 0; r < 4; ++r) {
        float g = gate[(size_t)(row0 + r) * NEXP + e];
        hg[(size_t)(row0 + r) * KCAT + j] = f2b(acc[m][n][r] * g);
      }
    }
  }
}

// ---------------- gemm2: y = xb@Wb^T + hg@BcatT^T + b  (concat K = 1024 | 256) ----------------
// 256x256 tile, BK=64, 8 waves (2Mx4N). R9: 3-phase K-tile with NO fragment re-reads
// (24 ds_read_b128/wave/K-tile vs R8's 32 — R8 was LDS-read-pipe-bound: 3072 cyc LDS vs
// 2483 cyc MFMA per CU per K-tile). bf frags live P0->P1b in regs. 6 barriers/K-tile.
// Counted vmcnt ledger and stageA race-free placement identical to R8 (proven).
#define KT2 20
#define KSW 16
__global__ __launch_bounds__(512, 2) void gemm2_kernel(const bf16* __restrict__ xb,
                                                       const bf16* __restrict__ Wb,
                                                       const float* __restrict__ bias,
                                                       const bf16* __restrict__ hg,
                                                       const bf16* __restrict__ BcatT,
                                                       float* __restrict__ out) {
  __shared__ alignas(16) bf16 As[2][256][64];   // 64 KiB
  __shared__ alignas(16) bf16 Bs[2][256][64];   // 64 KiB
  const int tid = threadIdx.x, wid = tid >> 6, lane = tid & 63;
  const int wm = wid >> 2, wn = wid & 3;        // 2 x 4 wave grid
  const int tileRow = blockIdx.x * 256, tileCol = blockIdx.y * 256;
  f32x4 acc[8][4] = {};

  // stage one half (h=0: rows 0-127, h=1: rows 128-255) of tile t (2 gload/thread)
  auto stageA = [&](int t, int h) {
    const bf16* p; size_t lda; int k0;
    if (t < KSW) { p = xb + (size_t)tileRow * DIN;  lda = DIN;  k0 = t * 64; }
    else         { p = hg + (size_t)tileRow * KCAT; lda = KCAT; k0 = (t - KSW) * 64; }
    const int buf = t & 1;
    #pragma unroll
    for (int rnd = 0; rnd < 2; ++rnd) {
      int rb = h * 128 + rnd * 64 + wid * 8;
      stage_swz(p + (size_t)rb * lda + k0, lda, &As[buf][rb][0], lane);
    }
  };
  auto stageB = [&](int t, int h) {
    const bf16* p; size_t lda; int k0;
    if (t < KSW) { p = Wb + (size_t)tileCol * DIN;     lda = DIN;  k0 = t * 64; }
    else         { p = BcatT + (size_t)tileCol * KCAT; lda = KCAT; k0 = (t - KSW) * 64; }
    const int buf = t & 1;
    #pragma unroll
    for (int rnd = 0; rnd < 2; ++rnd) {
      int rb = h * 128 + rnd * 64 + wid * 8;
      stage_swz(p + (size_t)rb * lda + k0, lda, &Bs[buf][rb][0], lane);
    }
  };
  // fragment reads (swizzled): row&7 == lane&7 since frag rows step by 16
  auto ldA = [&](int buf, int mf, int ks) -> short8 {
    int row = wm * 128 + mf * 16 + (lane & 15);
    int pc = ((ks * 4) + (lane >> 4)) ^ (lane & 7);
    return *(const short8*)&As[buf][row][pc * 8];
  };
  auto ldB = [&](int buf, int nf, int ks) -> short8 {
    int row = wn * 64 + nf * 16 + (lane & 15);
    int pc = ((ks * 4) + (lane >> 4)) ^ (lane & 7);
    return *(const short8*)&Bs[buf][row][pc * 8];
  };

  // ---- prologue: tile0 (4 halves) + tile1 A-halves; wait leaves A(1) in flight ----
  stageA(0, 0); stageA(0, 1); stageB(0, 0); stageB(0, 1);
  stageA(1, 0); stageA(1, 1);
  asm volatile("s_waitcnt vmcnt(4)" ::: "memory");
  __builtin_amdgcn_s_barrier();

  for (int t = 0; t < KT2; ++t) {
    const int cur = t & 1;
    short8 af[4][2], bf[4][2];

    // ---- P0: read af0 (mh0) + ALL bf; issue B(t+1); 32 MFMA (acc[0..3][0..3]) ----
    #pragma unroll
    for (int m = 0; m < 4; ++m)
      #pragma unroll
      for (int ks = 0; ks < 2; ++ks) af[m][ks] = ldA(cur, m, ks);
    #pragma unroll
    for (int n = 0; n < 4; ++n)
      #pragma unroll
      for (int ks = 0; ks < 2; ++ks) bf[n][ks] = ldB(cur, n, ks);
    if (t + 1 < KT2) { stageB(t + 1, 0); stageB(t + 1, 1); }
    __builtin_amdgcn_s_barrier();
    asm volatile("s_waitcnt lgkmcnt(0)" ::: "memory");
    __builtin_amdgcn_sched_barrier(0);
    __builtin_amdgcn_s_setprio(1);
    #pragma unroll
    for (int m = 0; m < 4; ++m)
      #pragma unroll
      for (int n = 0; n < 4; ++n)
        #pragma unroll
        for (int ks = 0; ks < 2; ++ks)
          acc[m][n] = __builtin_amdgcn_mfma_f32_16x16x32_bf16(af[m][ks], bf[n][ks], acc[m][n], 0, 0, 0);
    __builtin_amdgcn_s_setprio(0);
    __builtin_amdgcn_s_barrier();

    // ---- P1a: read af1 (mh1); 16 MFMA (acc[4..7][0..1]); bf reused from regs ----
    #pragma unroll
    for (int m = 0; m < 4; ++m)
      #pragma unroll
      for (int ks = 0; ks < 2; ++ks) af[m][ks] = ldA(cur, 4 + m, ks);
    __builtin_amdgcn_s_barrier();
    asm volatile("s_waitcnt lgkmcnt(0)" ::: "memory");
    __builtin_amdgcn_sched_barrier(0);
    __builtin_amdgcn_s_setprio(1);
    #pragma unroll
    for (int m = 0; m < 4; ++m)
      #pragma unroll
      for (int n = 0; n < 2; ++n)
        #pragma unroll
        for (int ks = 0; ks < 2; ++ks)
          acc[4 + m][n] = __builtin_amdgcn_mfma_f32_16x16x32_bf16(af[m][ks], bf[n][ks], acc[4 + m][n], 0, 0, 0);
    __builtin_amdgcn_s_setprio(0);
    __builtin_amdgcn_s_barrier();
    // ^ this barrier follows every wave's lgkmcnt(0) on its af1 reads -> safe to
    //   overwrite As[cur] after it (same WAR-protection pattern R8 proved).

    // ---- P1b: issue A(t+2) -> As[cur]; counted vmcnt; 16 MFMA (acc[4..7][2..3]), no reads ----
    if (t + 2 < KT2) { stageA(t + 2, 0); stageA(t + 2, 1); }
    if (t + 1 < KT2) {
      if (t + 2 < KT2) asm volatile("s_waitcnt vmcnt(4)" ::: "memory"); // A(t+1),B(t+1) done; A(t+2) in flight
      else             asm volatile("s_waitcnt vmcnt(0)" ::: "memory"); // tail
    }
    __builtin_amdgcn_s_barrier();
    __builtin_amdgcn_s_setprio(1);
    #pragma unroll
    for (int m = 0; m < 4; ++m)
      #pragma unroll
      for (int n = 0; n < 2; ++n)
        #pragma unroll
        for (int ks = 0; ks < 2; ++ks)
          acc[4 + m][2 + n] = __builtin_amdgcn_mfma_f32_16x16x32_bf16(af[m][ks], bf[2 + n][ks], acc[4 + m][2 + n], 0, 0, 0);
    __builtin_amdgcn_s_setprio(0);
    __builtin_amdgcn_s_barrier();
  }

  // ---- epilogue ----
  #pragma unroll
  for (int n = 0; n < 4; ++n) {
    int col = tileCol + wn * 64 + n * 16 + (lane & 15);
    float bb = bias[col];
    #pragma unroll
    for (int m = 0; m < 8; ++m) {
      int row0 = tileRow + wm * 128 + m * 16 + (lane >> 4) * 4;
      #pragma unroll
      for (int r = 0; r < 4; ++r)
        out[(size_t)(row0 + r) * DOUT + col] = acc[m][n][r] + bb;
    }
  }
}

extern "C" void kernel_launch(void* const* d_in, const int* in_sizes, int n_in,
                              void* d_out, int out_size, void* d_ws, size_t ws_size,
                              hipStream_t stream) {
  const float* x  = (const float*)d_in[0];
  const float* W  = (const float*)d_in[1];
  const float* bb = (const float*)d_in[2];
  const float* rW = (const float*)d_in[3];
  const float* rb = (const float*)d_in[4];
  const float* A  = (const float*)d_in[5];
  const float* Sa = (const float*)d_in[6];
  const float* B  = (const float*)d_in[7];
  const float* Sb = (const float*)d_in[8];
  float* out = (float*)d_out;

  char* ws = (char*)d_ws;
  float* gate  = (float*)ws;                            // 16384*8*4   = 512 KB
  bf16*  Acat  = (bf16*)(ws + (512 << 10));             // 256*1024*2  = 512 KB
  bf16*  BcatT = (bf16*)(ws + (1024 << 10));            // 1024*256*2  = 512 KB
  bf16*  Wb    = (bf16*)(ws + (1536 << 10));            // 1024*1024*2 = 2 MB
  bf16*  hg    = (bf16*)(ws + (3584 << 10));             // 16384*256*2 = 8 MB
  bf16*  xb    = (bf16*)(ws + (11776 << 10));            // 16384*1024*2 = 32 MB

  cvt_kernel<<<512, 256, 0, stream>>>(W, Wb, DOUT * DIN / 4);
  prep_kernel<<<512, 256, 0, stream>>>(A, Sa, B, Sb, Acat, BcatT);
  cvtrouter_kernel<<<TT / 4, 256, 0, stream>>>(x, rW, rb, xb, gate);
  gemm1_kernel<<<dim3(TT / 128, KCAT / 64), 256, 0, stream>>>(xb, Acat, gate, hg);
  gemm2_kernel<<<dim3(TT / 256, DOUT / 256), 512, 0, stream>>>(xb, Wb, bb, hg, BcatT, out);
}